// Round 1
// baseline (216.852 us; speedup 1.0000x reference)
//
#include <hip/hip_runtime.h>

// IPC point-edge barrier energy, MI355X.
// Inputs (setup_inputs order):
//   d_in[0] Uu              float32 [N_VERTS*2]
//   d_in[1] rest_positions  float32 [N_VERTS*2]
//   d_in[2] pair_v          int32   [N_PAIRS]
//   d_in[3] pair_e0         int32   [N_PAIRS]
//   d_in[4] pair_e1         int32   [N_PAIRS]
// Output: scalar float32 barrier energy.

constexpr int N_VERTS = 262144;
constexpr int N_PAIRS = 8388608;
constexpr float DHAT2 = 0.05f * 0.05f;       // 0.0025
constexpr float INV_DHAT2 = 1.0f / DHAT2;    // 400
constexpr float EPSF = 1e-12f;

// ---------------------------------------------------------------------------
// Kernel A: coords = rest + Uu  (524288 floats = 131072 float4)
// ---------------------------------------------------------------------------
__global__ __launch_bounds__(256) void coords_k(const float4* __restrict__ Uu,
                                                const float4* __restrict__ rest,
                                                float4* __restrict__ coords) {
    int i = blockIdx.x * blockDim.x + threadIdx.x;
    float4 u = Uu[i];
    float4 r = rest[i];
    coords[i] = make_float4(u.x + r.x, u.y + r.y, u.z + r.z, u.w + r.w);
}

// ---------------------------------------------------------------------------
// Kernel B: per-pair barrier + reduction.
// Grid-stride over quads of pairs; int4 coalesced index loads; float2 gathers
// hit the 2 MB coords table (L2-resident). Branchless barrier term.
// ---------------------------------------------------------------------------
__global__ __launch_bounds__(256) void pairs_k(const float2* __restrict__ coords,
                                               const int4* __restrict__ pv,
                                               const int4* __restrict__ pe0,
                                               const int4* __restrict__ pe1,
                                               float* __restrict__ out) {
    float acc = 0.0f;
    const int nquads = N_PAIRS / 4;
    const int stride = gridDim.x * blockDim.x;

    for (int q = blockIdx.x * blockDim.x + threadIdx.x; q < nquads; q += stride) {
        int4 v4 = pv[q];
        int4 a4 = pe0[q];
        int4 b4 = pe1[q];
        int vi[4] = {v4.x, v4.y, v4.z, v4.w};
        int ai[4] = {a4.x, a4.y, a4.z, a4.w};
        int bi[4] = {b4.x, b4.y, b4.z, b4.w};

#pragma unroll
        for (int k = 0; k < 4; ++k) {
            float2 p = coords[vi[k]];
            float2 a = coords[ai[k]];
            float2 b = coords[bi[k]];

            float abx = b.x - a.x, aby = b.y - a.y;
            float apx = p.x - a.x, apy = p.y - a.y;

            float denom = fmaxf(abx * abx + aby * aby, EPSF);
            float t = (apx * abx + apy * aby) / denom;
            t = fminf(fmaxf(t, 0.0f), 1.0f);

            float dx = apx - t * abx;
            float dy = apy - t * aby;
            float d2 = dx * dx + dy * dy;

            float d2s = fmaxf(d2, EPSF);
            float dm = d2s - DHAT2;
            float term = -(dm * dm) * __logf(d2s * INV_DHAT2);
            acc += (d2 < DHAT2) ? term : 0.0f;
        }
    }

    // wave (64-lane) shuffle reduction
#pragma unroll
    for (int off = 32; off > 0; off >>= 1)
        acc += __shfl_down(acc, off, 64);

    __shared__ float wsum[4];  // 256 threads = 4 waves
    int lane = threadIdx.x & 63;
    int wave = threadIdx.x >> 6;
    if (lane == 0) wsum[wave] = acc;
    __syncthreads();

    if (threadIdx.x == 0) {
        float s = wsum[0] + wsum[1] + wsum[2] + wsum[3];
        atomicAdd(out, s);
    }
}

// ---------------------------------------------------------------------------
extern "C" void kernel_launch(void* const* d_in, const int* in_sizes, int n_in,
                              void* d_out, int out_size, void* d_ws, size_t ws_size,
                              hipStream_t stream) {
    const float* Uu   = (const float*)d_in[0];
    const float* rest = (const float*)d_in[1];
    const int*   pv   = (const int*)d_in[2];
    const int*   pe0  = (const int*)d_in[3];
    const int*   pe1  = (const int*)d_in[4];
    float* out = (float*)d_out;

    float* coords = (float*)d_ws;  // 2 MB: N_VERTS * 2 floats

    // coords = rest + Uu
    {
        int nvec = (N_VERTS * 2) / 4;  // 131072
        coords_k<<<nvec / 256, 256, 0, stream>>>(
            (const float4*)Uu, (const float4*)rest, (float4*)coords);
    }

    // zero the accumulator (d_out is poisoned to 0xAA before every replay)
    hipMemsetAsync(d_out, 0, sizeof(float) * out_size, stream);

    // barrier energy
    {
        int blocks = 2048;  // 8 blocks/CU; one atomic per block
        pairs_k<<<blocks, 256, 0, stream>>>(
            (const float2*)coords, (const int4*)pv, (const int4*)pe0,
            (const int4*)pe1, out);
    }
}